// Round 3
// baseline (9100.050 us; speedup 1.0000x reference)
//
#include <hip/hip_runtime.h>
#include <math.h>

#define K_NN 11
#define B_   1024
#define D_   64
#define A_   4
#define C_   50000
#define NTA  782                 // ceil(C/64) total tiles
#define NCH  2
#define TPC  391                 // tiles per chunk (tile-aligned, disjoint)

// ---------------- K0: s2[a,c] = sum(ts[a,c,:]^2) ----------------
__global__ __launch_bounds__(256) void s2_kernel(const float* __restrict__ ts,
                                                 float* __restrict__ s2g) {
  const int gwid = (blockIdx.x * 256 + threadIdx.x) >> 6;
  const int lane = threadIdx.x & 63;
  const int r0 = gwid * 16;
  if (r0 >= A_ * C_) return;
  const float4* t4 = (const float4*)ts;
  #pragma unroll
  for (int i = 0; i < 4; ++i) {
    const int fi = i * 64 + lane;
    const int r  = r0 + (fi >> 4);
    const int k  = fi & 15;
    float4 v = t4[(size_t)r * 16 + k];
    float acc = v.x*v.x + v.y*v.y + v.z*v.z + v.w*v.w;
    #pragma unroll
    for (int off = 1; off < 16; off <<= 1) acc += __shfl_xor(acc, off, 64);
    if ((lane & 15) == 0) s2g[r] = acc;
  }
}

// ---------------- K1: transposed fused scores + shared-tau top-k ----------------
// grid 512 = 64 bg x 4 a x 2 ch, mapped so (a,ch)=bid&7 (XCD slice locality).
// 512 thr = 8 waves, wave = 2 b-rows; lane = candidate within 64-wide tile.

#define SELECT_INSERT(SCV, BEST, BIX, C0)                                   \
  {                                                                         \
    unsigned long long m_ = __ballot((SCV) < BEST[K_NN-1]);                 \
    while (m_) {                                                            \
      const int l_ = __ffsll(m_) - 1;                                       \
      m_ &= m_ - 1;                                                         \
      const float ssc = __uint_as_float(                                    \
          __builtin_amdgcn_readlane(__float_as_uint(SCV), l_));             \
      const int sidx = (C0) + l_;                                           \
      if (ssc < BEST[K_NN-1]) {                                             \
        _Pragma("unroll")                                                   \
        for (int j = K_NN-1; j >= 1; --j) {                                 \
          const bool  sh = BEST[j-1] > ssc;                                 \
          const float nb = sh ? BEST[j-1] : ssc;                            \
          const int   ni = sh ? BIX[j-1]  : sidx;                           \
          const bool  wr = BEST[j] > ssc;                                   \
          BEST[j] = wr ? nb : BEST[j];                                      \
          BIX[j]  = wr ? ni : BIX[j];                                       \
        }                                                                   \
        const bool w0 = BEST[0] > ssc;                                      \
        BIX[0]  = w0 ? sidx : BIX[0];                                       \
        BEST[0] = w0 ? ssc  : BEST[0];                                      \
      }                                                                     \
    }                                                                       \
  }

__global__ __launch_bounds__(512, 4) void qec_kernel(
    const float* __restrict__ obs, const float* __restrict__ ts,
    const float* __restrict__ s2g, float* __restrict__ pscore,
    int* __restrict__ pidx)
{
  __shared__ float sbuf[2][64 * 64];        // 2 x 16KB, swizzled float4 slots

  const int tid  = threadIdx.x;
  const int lane = tid & 63;
  const int w    = tid >> 6;
  const int a    = blockIdx.x & 3;          // (a,ch) = bid&7 -> XCD locality
  const int ch   = (blockIdx.x >> 2) & 1;
  const int bg   = blockIdx.x >> 3;
  const int b0   = bg * 16 + w * 2;
  const int b1   = b0 + 1;

  const float* tsa = ts  + (size_t)a * C_ * 64;
  const float* s2a = s2g + (size_t)a * C_;

  // obs rows -> broadcast regs (AGPR-backed ok)
  float o0[64], o1[64];
  {
    const float4* p0 = (const float4*)(obs + (size_t)b0 * 64);
    const float4* p1 = (const float4*)(obs + (size_t)b1 * 64);
    #pragma unroll
    for (int i = 0; i < 16; ++i) {
      float4 v0 = p0[i], v1 = p1[i];
      o0[4*i]=v0.x; o0[4*i+1]=v0.y; o0[4*i+2]=v0.z; o0[4*i+3]=v0.w;
      o1[4*i]=v1.x; o1[4*i+1]=v1.y; o1[4*i+2]=v1.z; o1[4*i+3]=v1.w;
    }
  }

  float best0[K_NN], best1[K_NN]; int bix0[K_NN], bix1[K_NN];
  #pragma unroll
  for (int j = 0; j < K_NN; ++j) {
    best0[j] = INFINITY; best1[j] = INFINITY; bix0[j] = 0; bix1[j] = 0;
  }

  // staging: linear global col (coalesced), swizzled LDS write slot
  const int sl0 = w * 64 + lane;            // linear slot 0..511
  const int sl1 = sl0 + 512;                // 512..1023
  const int r0s = sl0 >> 4, k0 = sl0 & 15;
  const int r1s = sl1 >> 4, k1 = sl1 & 15;
  const int ws0 = r0s * 16 + (k0 ^ (r0s & 15));
  const int ws1 = r1s * 16 + (k1 ^ (r1s & 15));

  const int t0 = ch * TPC;                  // chunk tile range [t0, t0+TPC)

  // prologue: load tile t0 into regs
  float4 st0, st1;
  {
    int c0r0 = t0 * 64 + r0s; if (c0r0 > C_-1) c0r0 = C_-1;
    int c0r1 = t0 * 64 + r1s; if (c0r1 > C_-1) c0r1 = C_-1;
    st0 = *(const float4*)(tsa + (size_t)c0r0 * 64 + k0 * 4);
    st1 = *(const float4*)(tsa + (size_t)c0r1 * 64 + k1 * 4);
  }

  for (int i = 0; i < TPC; ++i) {
    const int t   = t0 + i;
    const int c0  = t * 64;
    const int buf = i & 1;

    float4* sp = (float4*)&sbuf[buf][0];
    sp[ws0] = st0; sp[ws1] = st1;

    // issue next tile's global loads early (clamped)
    {
      int tn = t + 1; if (tn > t0 + TPC - 1) tn = t0 + TPC - 1;
      int cn0 = tn * 64 + r0s; if (cn0 > C_-1) cn0 = C_-1;
      int cn1 = tn * 64 + r1s; if (cn1 > C_-1) cn1 = C_-1;
      st0 = *(const float4*)(tsa + (size_t)cn0 * 64 + k0 * 4);
      st1 = *(const float4*)(tsa + (size_t)cn1 * 64 + k1 * 4);
    }
    int cs2 = c0 + lane; if (cs2 > C_-1) cs2 = C_-1;
    const float s2v = s2a[cs2];

    __syncthreads();

    float acc0a = 0.f, acc0b = 0.f, acc0c = 0.f, acc0d = 0.f;
    float acc1a = 0.f, acc1b = 0.f, acc1c = 0.f, acc1d = 0.f;
    const float4* rp = (const float4*)&sbuf[buf][0];
    #pragma unroll
    for (int d4 = 0; d4 < 16; ++d4) {
      const float4 cv = rp[lane * 16 + (d4 ^ (lane & 15))];
      acc0a = fmaf(cv.x, o0[4*d4+0], acc0a);
      acc1a = fmaf(cv.x, o1[4*d4+0], acc1a);
      acc0b = fmaf(cv.y, o0[4*d4+1], acc0b);
      acc1b = fmaf(cv.y, o1[4*d4+1], acc1b);
      acc0c = fmaf(cv.z, o0[4*d4+2], acc0c);
      acc1c = fmaf(cv.z, o1[4*d4+2], acc1c);
      acc0d = fmaf(cv.w, o0[4*d4+3], acc0d);
      acc1d = fmaf(cv.w, o1[4*d4+3], acc1d);
    }
    const bool valid = (c0 + lane) < C_;
    float dot0 = (acc0a + acc0b) + (acc0c + acc0d);
    float dot1 = (acc1a + acc1b) + (acc1c + acc1d);
    float sc0 = fmaf(-2.f, dot0, s2v);
    float sc1 = fmaf(-2.f, dot1, s2v);
    sc0 = valid ? sc0 : INFINITY;
    sc1 = valid ? sc1 : INFINITY;
    SELECT_INSERT(sc0, best0, bix0, c0);
    SELECT_INSERT(sc1, best1, bix1, c0);

    __syncthreads();
  }

  // write partial lists: [(b*A + a)*NCH + ch]*K
  if (lane == 0) {
    const size_t base0 = (((size_t)b0 * A_ + a) * NCH + ch) * K_NN;
    const size_t base1 = (((size_t)b1 * A_ + a) * NCH + ch) * K_NN;
    #pragma unroll
    for (int j = 0; j < K_NN; ++j) {
      pscore[base0+j] = best0[j]; pidx[base0+j] = bix0[j];
      pscore[base1+j] = best1[j]; pidx[base1+j] = bix1[j];
    }
  }
}

// ---------------- K2: merge partial top-k, gather qvals, mean ----------------
__global__ __launch_bounds__(256) void merge_kernel(
    const float* __restrict__ pscore, const int* __restrict__ pidx,
    const float* __restrict__ qvals, float* __restrict__ qec)
{
  const int tt = blockIdx.x * 256 + threadIdx.x;  // tt = b*A + a
  if (tt >= B_ * A_) return;
  const int a = tt % A_;

  float best[K_NN]; int bix[K_NN];
  #pragma unroll
  for (int j = 0; j < K_NN; ++j) { best[j] = INFINITY; bix[j] = 0x7fffffff; }

  const float* ps = pscore + (size_t)tt * NCH * K_NN;
  const int*   pi = pidx   + (size_t)tt * NCH * K_NN;

  #pragma unroll
  for (int e = 0; e < NCH * K_NN; ++e) {
    float sc = ps[e]; int ci = pi[e];
    bool lt_last = (sc < best[K_NN-1]) || (sc == best[K_NN-1] && ci < bix[K_NN-1]);
    if (lt_last) {
      #pragma unroll
      for (int j = K_NN-1; j >= 1; --j) {
        bool  s1 = (best[j-1] > sc) || (best[j-1] == sc && bix[j-1] > ci);
        float nb = s1 ? best[j-1] : sc;
        int   ni = s1 ? bix[j-1]  : ci;
        bool  wr = (best[j] > sc) || (best[j] == sc && bix[j] > ci);
        if (wr) { best[j] = nb; bix[j] = ni; }
      }
      bool w0 = (best[0] > sc) || (best[0] == sc && bix[0] > ci);
      if (w0) { best[0] = sc; bix[0] = ci; }
    }
  }

  const float* qa = qvals + (size_t)a * C_;
  float s = 0.f;
  #pragma unroll
  for (int j = 0; j < K_NN; ++j) s += qa[bix[j]];
  qec[tt] = s / (float)K_NN;
}

// ---------------- K3: MLP + combine + argmax ----------------
__global__ __launch_bounds__(256) void mlp_kernel(
    const float* __restrict__ obs, const float* __restrict__ qec,
    const float* __restrict__ W1, const float* __restrict__ b1,
    const float* __restrict__ W2, const float* __restrict__ b2,
    const float* __restrict__ W3, const float* __restrict__ b3,
    float* __restrict__ out)
{
  const int wave = threadIdx.x >> 6;
  const int lane = threadIdx.x & 63;
  const int b = blockIdx.x * 4 + wave;

  float x = obs[(size_t)b * 64 + lane];

  float acc = b1[lane];
  #pragma unroll 8
  for (int d = 0; d < 64; ++d)
    acc = fmaf(__shfl(x, d, 64), W1[d * 64 + lane], acc);
  float h1 = fmaxf(acc, 0.f);

  float acc2 = b2[lane];
  #pragma unroll 8
  for (int d = 0; d < 64; ++d)
    acc2 = fmaf(__shfl(h1, d, 64), W2[d * 64 + lane], acc2);
  float h2 = fmaxf(acc2, 0.f);

  float p0 = h2 * W3[lane * 4 + 0];
  float p1 = h2 * W3[lane * 4 + 1];
  float p2 = h2 * W3[lane * 4 + 2];
  float p3 = h2 * W3[lane * 4 + 3];
  #pragma unroll
  for (int off = 32; off > 0; off >>= 1) {
    p0 += __shfl_xor(p0, off, 64);
    p1 += __shfl_xor(p1, off, 64);
    p2 += __shfl_xor(p2, off, 64);
    p3 += __shfl_xor(p3, off, 64);
  }

  if (lane == 0) {
    float q0 = 0.5f * (qec[b * 4 + 0] + (p0 + b3[0]));
    float q1 = 0.5f * (qec[b * 4 + 1] + (p1 + b3[1]));
    float q2 = 0.5f * (qec[b * 4 + 2] + (p2 + b3[2]));
    float q3 = 0.5f * (qec[b * 4 + 3] + (p3 + b3[3]));
    int am = 0; float m = q0;
    if (q1 > m) { m = q1; am = 1; }
    if (q2 > m) { m = q2; am = 2; }
    if (q3 > m) { m = q3; am = 3; }
    out[b] = (float)am;
    float* qrow = out + B_ + (size_t)b * 4;
    qrow[0] = q0; qrow[1] = q1; qrow[2] = q2; qrow[3] = q3;
  }
}

extern "C" void kernel_launch(void* const* d_in, const int* in_sizes, int n_in,
                              void* d_out, int out_size, void* d_ws, size_t ws_size,
                              hipStream_t stream) {
  const float* obs = (const float*)d_in[0];
  const float* ts  = (const float*)d_in[1];
  const float* qv  = (const float*)d_in[2];
  const float* W1  = (const float*)d_in[3];
  const float* b1  = (const float*)d_in[4];
  const float* W2  = (const float*)d_in[5];
  const float* b2  = (const float*)d_in[6];
  const float* W3  = (const float*)d_in[7];
  const float* b3  = (const float*)d_in[8];
  float* out = (float*)d_out;

  float* s2g    = (float*)d_ws;                                   // A*C
  float* qec    = s2g + (size_t)A_ * C_;                          // B*A
  float* pscore = qec + (size_t)B_ * A_;                          // B*A*NCH*K
  int*   pidx   = (int*)(pscore + (size_t)B_ * A_ * NCH * K_NN);  // same

  s2_kernel<<<dim3((A_ * C_ / 16 + 3) / 4), dim3(256), 0, stream>>>(ts, s2g);
  qec_kernel<<<dim3(512), dim3(512), 0, stream>>>(obs, ts, s2g, pscore, pidx);
  merge_kernel<<<dim3((B_ * A_ + 255) / 256), dim3(256), 0, stream>>>(pscore, pidx, qv, qec);
  mlp_kernel<<<dim3(B_ / 4), dim3(256), 0, stream>>>(obs, qec, W1, b1, W2, b2, W3, b3, out);
}